// Round 6
// baseline (476.302 us; speedup 1.0000x reference)
//
#include <hip/hip_runtime.h>
#include <hip/hip_bf16.h>
#include <math.h>

typedef __attribute__((ext_vector_type(8))) short short8;
typedef __attribute__((ext_vector_type(16))) float f32x16;

static constexpr int B  = 32;
static constexpr int S  = 2048;
static constexpr int D  = 512;
static constexpr int KE = 1024;   // encoder feature dim = 2*ENC_H
static constexpr int IN = 1536;   // D + KE

__device__ __forceinline__ unsigned pk2(float lo, float hi) {
    __hip_bfloat162 t = __float22bfloat162_rn(make_float2(lo, hi));
    unsigned u;
    __builtin_memcpy(&u, &t, 4);
    return u;
}

__device__ __forceinline__ short8 pack8(float4 f0, float4 f1) {
    unsigned u[4] = { pk2(f0.x, f0.y), pk2(f0.z, f0.w), pk2(f1.x, f1.y), pk2(f1.z, f1.w) };
    short8 r;
    __builtin_memcpy(&r, u, 16);
    return r;
}

// fast tanh via exp: (e^2x - 1)/(e^2x + 1)
__device__ __forceinline__ float tanh_fast(float x) {
    float e = __expf(2.0f * x);
    return (e - 1.0f) * __builtin_amdgcn_rcpf(e + 1.0f);
}

// ---------- kernel 0: fused prep (B-frag pack + u projection + ws zeroing) ----------
__global__ void k_prep(const float* __restrict__ attn_w,
                       const float* __restrict__ hidden,
                       const float* __restrict__ attn_b,
                       unsigned short* __restrict__ Bf,
                       float* __restrict__ u,
                       float* __restrict__ num,
                       float* __restrict__ den) {
    if (blockIdx.x < 256) {
        int o = blockIdx.x * 256 + threadIdx.x;   // short8 index, 65536 total
        int l6  = o & 63;
        int grp = o >> 6;
        int d = (grp & 15) * 32 + (l6 & 31);
        int k = (grp >> 4) * 16 + (l6 >> 5) * 8;
        const float* src = attn_w + (size_t)d * IN + 512 + k;
        float4 f0 = *(const float4*)src;
        float4 f1 = *(const float4*)(src + 4);
        ((short8*)Bf)[o] = pack8(f0, f1);
    } else {
        // u[b][d] = attn_b[d] + dot(hidden[b], attn_w[d][0:512])
        // 256 blocks: 8 per batch (64 d's each); 16 lanes cooperate per d
        int bx = blockIdx.x - 256;        // 0..255
        // ---- workspace zeroing (replaces hipMemsetAsync dispatch) ----
        if (bx < 64) {
            int gid = bx * 256 + threadIdx.x;             // 0..16383
            ((float2*)num)[gid] = make_float2(0.f, 0.f);  // 32768 floats
            if (bx == 0 && threadIdx.x < 32) den[threadIdx.x] = 0.f;
        }
        int b  = bx >> 3;                 // 0..31
        int dh = bx & 7;                  // 64-d slice
        int w  = threadIdx.x >> 6;        // wave 0..3
        int l  = threadIdx.x & 63;
        int j  = l & 15;                  // k-segment lane
        int dsub = l >> 4;                // 0..3 (d within wave-group)
        const float* h = hidden + b * D;
        float4 hv[8];
        #pragma unroll
        for (int i = 0; i < 8; i++) hv[i] = *(const float4*)(h + i * 64 + j * 4);
        #pragma unroll
        for (int p = 0; p < 4; p++) {
            int d = dh * 64 + p * 16 + w * 4 + dsub;
            const float* wr = attn_w + (size_t)d * IN + j * 4;
            float a = 0.f;
            #pragma unroll
            for (int i = 0; i < 8; i++) {
                float4 wv = *(const float4*)(wr + i * 64);
                a += hv[i].x * wv.x + hv[i].y * wv.y + hv[i].z * wv.z + hv[i].w * wv.w;
            }
            #pragma unroll
            for (int off = 8; off >= 1; off >>= 1) a += __shfl_xor(a, off);
            if (j == 0) u[b * D + d] = a + attn_b[d];
        }
    }
}

// ---------- kernel 1: FUSED scores + exp + context-accumulate ----------
// Single-phase staging: wave w streams its contiguous 64 KB region (16 full
// 4 KB rows, coalesced 32 B/lane) -> bf16 tile in 128 KB LDS. ONE barrier.
// Compute phase's only outstanding vmcnt loads are the L2 Bfrag streams, so
// pb uses never wait behind HBM traffic (the in-order-vmcnt serialization
// that capped all chunked variants at ~900 GB/s). bf16 convert at stage time.
// Tile swizzle: 16B-unit phys = u ^ (row & 7) -> A-frag column reads at the
// 4-way floor; stage writes stay conflict-free (whole wave on one row).
#define LOADB(K, DST) do {                                     \
    _Pragma("unroll")                                          \
    for (int _jt = 0; _jt < 4; _jt++)                          \
        DST[_jt] = bb[(size_t)(K) * 1024 + _jt * 64];          \
} while (0)

__global__ __launch_bounds__(256, 1) void k_fused(
    const float* __restrict__ enc, const unsigned short* __restrict__ Bfrag,
    const float* __restrict__ u, const float* __restrict__ v_w,
    const float* __restrict__ v_b, const int* __restrict__ lengths,
    float* __restrict__ num, float* __restrict__ den)
{
    __shared__ short8 tile[64 * 128];   // 128 KB bf16 [row][unit ^ (row&7)]
    __shared__ float sPart[4][64];
    __shared__ float sExp[64];

    const int b   = blockIdx.y;
    const int s0  = blockIdx.x * 64;
    const int len = lengths[b];
    if (s0 >= len) return;

    const int tid = threadIdx.x;
    const int w   = tid >> 6;     // wave 0..3
    const int l   = tid & 63;     // lane

    const float* encb = enc + ((size_t)b * S + s0) * KE;
    const short8* bb = (const short8*)Bfrag + (w * 4) * 64 + l;

    // prefetch first two B k-steps BEFORE staging (FIFO: [B][staging]) so
    // pb[0/1] are complete long before first use
    short8 pb[2][4];
    LOADB(0, pb[0]);
    LOADB(1, pb[1]);

    // ---- stage: wave w -> rows 16w..16w+15 (contiguous 64 KB global) ----
    {
        const float* src0 = encb + (size_t)(16 * w) * KE + l * 8;
        #pragma unroll 4
        for (int i = 0; i < 32; ++i) {
            int r = 16 * w + (i >> 1);
            const float* s = src0 + (size_t)(i >> 1) * KE + (i & 1) * 512;
            float4 f0 = *(const float4*)s;
            float4 f1 = *(const float4*)(s + 4);
            int un = (i & 1) * 64 + l;           // logical 16B unit in row
            tile[r * 128 + (un ^ (r & 7))] = pack8(f0, f1);
        }
    }

    f32x16 acc[2][4];
    #pragma unroll
    for (int mt = 0; mt < 2; mt++)
        #pragma unroll
        for (int jt = 0; jt < 4; jt++)
            #pragma unroll
            for (int e = 0; e < 16; e++) acc[mt][jt][e] = 0.f;

    // A-frag read constants: lane reads rows m0, m0+32; k-step t -> logical
    // unit t*2 + (l>>5); phys = u ^ (m0&7)  ((m0+32)&7 == m0&7)
    const int m0 = l & 31;
    const int xr = m0 & 7;
    const int hi = l >> 5;
    const short8* rowA = tile + m0 * 128;
    const short8* rowB = tile + (m0 + 32) * 128;

    __syncthreads();   // staging complete; tile visible to all waves

    #pragma unroll 4
    for (int t = 0; t < 64; ++t) {
        const int p = (t * 2 + hi) ^ xr;
        short8 a0 = rowA[p];
        short8 a1 = rowB[p];
        const int bp = t & 1;
        #pragma unroll
        for (int jt = 0; jt < 4; jt++) {
            acc[0][jt] = __builtin_amdgcn_mfma_f32_32x32x16_bf16(a0, pb[bp][jt], acc[0][jt], 0, 0, 0);
            acc[1][jt] = __builtin_amdgcn_mfma_f32_32x32x16_bf16(a1, pb[bp][jt], acc[1][jt], 0, 0, 0);
        }
        LOADB((t + 2) & 63, pb[bp]);
    }

    // ---- epilogue A: score_part = sum_d v[d]*tanh(pre + u[d]) ----
    // C/D layout (32x32): col = lane&31, row = (reg&3) + 8*(reg>>2) + 4*(lane>>5)
    float vv[4], uu[4];
    const float* ub = u + b * D;
    #pragma unroll
    for (int jt = 0; jt < 4; jt++) {
        int d = w * 128 + jt * 32 + (l & 31);
        vv[jt] = v_w[d];
        uu[jt] = ub[d];
    }
    float red[2][16];
    #pragma unroll
    for (int mt = 0; mt < 2; mt++)
        #pragma unroll
        for (int r = 0; r < 16; r++) {
            float s = 0.f;
            #pragma unroll
            for (int jt = 0; jt < 4; jt++)
                s += vv[jt] * tanh_fast(acc[mt][jt][r] + uu[jt]);
            red[mt][r] = s;
        }
    #pragma unroll
    for (int off = 16; off >= 1; off >>= 1)
        #pragma unroll
        for (int mt = 0; mt < 2; mt++)
            #pragma unroll
            for (int r = 0; r < 16; r++)
                red[mt][r] += __shfl_xor(red[mt][r], off);
    if ((l & 31) == 0) {
        int hb = (l >> 5) * 4;
        #pragma unroll
        for (int mt = 0; mt < 2; mt++)
            #pragma unroll
            for (int r = 0; r < 16; r++)
                sPart[w][mt * 32 + (r & 3) + 8 * (r >> 2) + hb] = red[mt][r];
    }
    __syncthreads();

    // ---- epilogue B: w = exp(score) (|score|<=~23, no max needed), masked; den ----
    if (tid < 64) {
        float sc = sPart[0][tid] + sPart[1][tid] + sPart[2][tid] + sPart[3][tid] + v_b[0];
        float wexp = (s0 + tid < len) ? __expf(sc) : 0.f;
        sExp[tid] = wexp;
        #pragma unroll
        for (int off = 32; off >= 1; off >>= 1) wexp += __shfl_xor(wexp, off);
        if (tid == 0) atomicAdd(den + b, wexp);
    }
    __syncthreads();

    // ---- epilogue C: num[b][e] += sum_s w_s * enc[s][e] (enc L3-warm fp32) ----
    const float4* e4 = (const float4*)encb;
    float4 cacc[4];
    #pragma unroll
    for (int j = 0; j < 4; j++) cacc[j] = make_float4(0.f, 0.f, 0.f, 0.f);
    #pragma unroll
    for (int i = 0; i < 16; i++) {
        #pragma unroll
        for (int j = 0; j < 4; j++) {
            float wgt = sExp[i * 4 + j];
            float4 v = e4[(size_t)(i * 4 + j) * 256 + tid];
            cacc[j].x += wgt * v.x; cacc[j].y += wgt * v.y;
            cacc[j].z += wgt * v.z; cacc[j].w += wgt * v.w;
        }
    }
    #pragma unroll
    for (int j = 1; j < 4; j++) {
        cacc[0].x += cacc[j].x; cacc[0].y += cacc[j].y;
        cacc[0].z += cacc[j].z; cacc[0].w += cacc[j].w;
    }
    float* o = num + b * KE + tid * 4;
    atomicAdd(o + 0, cacc[0].x);
    atomicAdd(o + 1, cacc[0].y);
    atomicAdd(o + 2, cacc[0].z);
    atomicAdd(o + 3, cacc[0].w);
}

// ---------- kernel 2: out = num / den ----------
__global__ void k_norm(const float* __restrict__ num, const float* __restrict__ den,
                       float* __restrict__ out) {
    int b = blockIdx.x;
    int t = threadIdx.x;
    float inv = 1.f / den[b];
    float4 v = ((const float4*)(num + b * KE))[t];
    v.x *= inv; v.y *= inv; v.z *= inv; v.w *= inv;
    ((float4*)(out + b * KE))[t] = v;
}

extern "C" void kernel_launch(void* const* d_in, const int* in_sizes, int n_in,
                              void* d_out, int out_size, void* d_ws, size_t ws_size,
                              hipStream_t stream) {
    const float* enc    = (const float*)d_in[0];
    const float* hidden = (const float*)d_in[1];
    const int*   lengths= (const int*)d_in[2];
    const float* attn_w = (const float*)d_in[3];
    const float* attn_b = (const float*)d_in[4];
    const float* v_w    = (const float*)d_in[5];
    const float* v_b    = (const float*)d_in[6];
    float* out = (float*)d_out;

    // workspace layout (fp32 elements)
    float* ws  = (float*)d_ws;
    float* u   = ws;                        // 16384 floats
    float* num = u + B * D;                 // B*KE = 32768 floats
    float* den = num + B * KE;              // 32 floats
    unsigned short* Bf = (unsigned short*)(den + 32);  // 524288 bf16 = 1MB (16B-aligned)

    k_prep <<<dim3(512), 256, 0, stream>>>(attn_w, hidden, attn_b, Bf, u, num, den);
    k_fused<<<dim3(S / 64, B), 256, 0, stream>>>(enc, Bf, u, v_w, v_b, lengths, num, den);
    k_norm <<<dim3(B), 256, 0, stream>>>(num, den, out);
}